// Round 1
// baseline (9405.289 us; speedup 1.0000x reference)
//
#include <hip/hip_runtime.h>

// RVQ inference: B=16, C=64, N=4096, Q=8, K=8192, fp32.
// Outputs (concat, float32): out[B,C,N], indices[B,N,Q] (as float), mean loss (1).
// ws layout: [0 .. Q*K) = cbsq (float), [Q*K] = loss accumulator (float).

constexpr int Bn = 16, Cn = 64, Nn = 4096, Qn = 8, Kn = 8192;
constexpr int PTS = 64;                 // points per block (one per lane)
constexpr int CHUNK = 128;              // codebook rows staged per LDS chunk
constexpr int NCHUNK = Kn / CHUNK;      // 64
constexpr int ROWS_PER_WAVE = CHUNK / 4;// 32

__global__ __launch_bounds__(256) void cbsq_kernel(const float* __restrict__ cb,
                                                   float* __restrict__ ws) {
    int row = blockIdx.x * 256 + threadIdx.x;   // 0 .. Q*K-1
    if (row == 0) ws[Qn * Kn] = 0.0f;           // zero loss accumulator (stream-ordered before main)
    if (row < Qn * Kn) {
        const float4* r = (const float4*)(cb + (size_t)row * Cn);
        float s = 0.0f;
#pragma unroll
        for (int i = 0; i < 16; ++i) {
            float4 v = r[i];
            s = fmaf(v.x, v.x, s); s = fmaf(v.y, v.y, s);
            s = fmaf(v.z, v.z, s); s = fmaf(v.w, v.w, s);
        }
        ws[row] = s;
    }
}

__global__ __launch_bounds__(256, 4) void rvq_kernel(
    const float* __restrict__ x, const float* __restrict__ cb,
    const float* __restrict__ cbsq, float* __restrict__ out,
    float* __restrict__ loss_acc) {
    __shared__ float lds_cb[CHUNK * Cn];
    __shared__ float lds_sq[CHUNK];
    __shared__ float red_d[4][PTS];
    __shared__ int   red_k[4][PTS];

    const int tid  = threadIdx.x;
    const int wave = tid >> 6;
    const int lane = tid & 63;
    const int gp   = blockIdx.x * PTS + lane;   // global point id = b*N + n
    const int b    = gp >> 12;                  // N = 4096
    const int n    = gp & (Nn - 1);
    const float* xp = x + (size_t)b * Cn * Nn + n;

    float res[Cn];
#pragma unroll
    for (int c = 0; c < Cn; ++c) res[c] = xp[(size_t)c * Nn];

    float loss_pt = 0.0f;

    for (int q = 0; q < Qn; ++q) {
        const float* cbq = cb + (size_t)q * Kn * Cn;
        float best_d = 3.4e38f;
        int   best_k = 0;

        for (int ch = 0; ch < NCHUNK; ++ch) {
            __syncthreads();                      // previous chunk fully consumed
            // stage 128 rows (32 KB), coalesced float4
            const float4* src = (const float4*)(cbq + (size_t)ch * CHUNK * Cn);
            float4* dst = (float4*)lds_cb;
#pragma unroll
            for (int i = 0; i < (CHUNK * Cn / 4) / 256; ++i)
                dst[tid + i * 256] = src[tid + i * 256];
            if (tid < CHUNK) lds_sq[tid] = cbsq[q * Kn + ch * CHUNK + tid];
            __syncthreads();

            const int rbase = wave * ROWS_PER_WAVE;
            for (int r0 = 0; r0 < ROWS_PER_WAVE; r0 += 4) {
                const float4* p0 = (const float4*)(lds_cb + (rbase + r0 + 0) * Cn);
                const float4* p1 = (const float4*)(lds_cb + (rbase + r0 + 1) * Cn);
                const float4* p2 = (const float4*)(lds_cb + (rbase + r0 + 2) * Cn);
                const float4* p3 = (const float4*)(lds_cb + (rbase + r0 + 3) * Cn);
                float a0 = 0.f, a1 = 0.f, a2 = 0.f, a3 = 0.f;
#pragma unroll
                for (int i = 0; i < 16; ++i) {
                    float4 v0 = p0[i], v1 = p1[i], v2 = p2[i], v3 = p3[i];
                    const float w0 = res[4 * i + 0], w1 = res[4 * i + 1];
                    const float w2 = res[4 * i + 2], w3 = res[4 * i + 3];
                    a0 = fmaf(w0, v0.x, a0); a0 = fmaf(w1, v0.y, a0);
                    a0 = fmaf(w2, v0.z, a0); a0 = fmaf(w3, v0.w, a0);
                    a1 = fmaf(w0, v1.x, a1); a1 = fmaf(w1, v1.y, a1);
                    a1 = fmaf(w2, v1.z, a1); a1 = fmaf(w3, v1.w, a1);
                    a2 = fmaf(w0, v2.x, a2); a2 = fmaf(w1, v2.y, a2);
                    a2 = fmaf(w2, v2.z, a2); a2 = fmaf(w3, v2.w, a2);
                    a3 = fmaf(w0, v3.x, a3); a3 = fmaf(w1, v3.y, a3);
                    a3 = fmaf(w2, v3.z, a3); a3 = fmaf(w3, v3.w, a3);
                }
                const int kb = ch * CHUNK + rbase + r0;
                float d0 = lds_sq[rbase + r0 + 0] - 2.0f * a0;
                float d1 = lds_sq[rbase + r0 + 1] - 2.0f * a1;
                float d2 = lds_sq[rbase + r0 + 2] - 2.0f * a2;
                float d3 = lds_sq[rbase + r0 + 3] - 2.0f * a3;
                // strict < keeps the FIRST (lowest-k) minimum, matching jnp.argmin
                if (d0 < best_d) { best_d = d0; best_k = kb + 0; }
                if (d1 < best_d) { best_d = d1; best_k = kb + 1; }
                if (d2 < best_d) { best_d = d2; best_k = kb + 2; }
                if (d3 < best_d) { best_d = d3; best_k = kb + 3; }
            }
        }

        // combine the 4 wave-local argmins (K was split 4-way across waves)
        red_d[wave][lane] = best_d;
        red_k[wave][lane] = best_k;
        __syncthreads();
        float bd = red_d[0][lane];
        int   bk = red_k[0][lane];
#pragma unroll
        for (int w = 1; w < 4; ++w) {
            float d2w = red_d[w][lane];
            int   k2w = red_k[w][lane];
            if (d2w < bd || (d2w == bd && k2w < bk)) { bd = d2w; bk = k2w; }
        }

        if (wave == 0)
            out[(size_t)(Bn * Cn * Nn) + (size_t)gp * Qn + q] = (float)bk;

        // residual update (gather winning code row; codebook is L2-hot)
        const float4* crow = (const float4*)(cbq + (size_t)bk * Cn);
        float ss = 0.0f;
#pragma unroll
        for (int i = 0; i < 16; ++i) {
            float4 v = crow[i];
            res[4 * i + 0] -= v.x; res[4 * i + 1] -= v.y;
            res[4 * i + 2] -= v.z; res[4 * i + 3] -= v.w;
            ss = fmaf(res[4 * i + 0], res[4 * i + 0], ss);
            ss = fmaf(res[4 * i + 1], res[4 * i + 1], ss);
            ss = fmaf(res[4 * i + 2], res[4 * i + 2], ss);
            ss = fmaf(res[4 * i + 3], res[4 * i + 3], ss);
        }
        loss_pt += ss;   // Σ_q |new residual|^2 ; same weight each q
    }

    if (wave == 0) {
        // quantized = x - final residual ; out[b][c][n], coalesced over n (lanes)
#pragma unroll
        for (int c = 0; c < Cn; ++c)
            out[((size_t)b * Cn + c) * Nn + n] = xp[(size_t)c * Nn] - res[c];
        // block loss: wave-64 shuffle reduce, one atomic per block
        float s = loss_pt;
#pragma unroll
        for (int off = 32; off > 0; off >>= 1) s += __shfl_down(s, off, 64);
        if (lane == 0) atomicAdd(loss_acc, s);
    }
}

__global__ void final_kernel(const float* __restrict__ loss_acc,
                             float* __restrict__ out) {
    out[(size_t)Bn * Cn * Nn + (size_t)Bn * Nn * Qn] =
        loss_acc[0] * (1.0f / ((float)Qn * Bn * Nn * Cn));
}

extern "C" void kernel_launch(void* const* d_in, const int* in_sizes, int n_in,
                              void* d_out, int out_size, void* d_ws, size_t ws_size,
                              hipStream_t stream) {
    const float* x  = (const float*)d_in[0];
    const float* cb = (const float*)d_in[1];
    float* out = (float*)d_out;
    float* ws  = (float*)d_ws;

    hipLaunchKernelGGL(cbsq_kernel, dim3((Qn * Kn) / 256), dim3(256), 0, stream, cb, ws);
    hipLaunchKernelGGL(rvq_kernel, dim3((Bn * Nn) / PTS), dim3(256), 0, stream,
                       x, cb, ws, out, ws + Qn * Kn);
    hipLaunchKernelGGL(final_kernel, dim3(1), dim3(1), 0, stream, ws + Qn * Kn, out);
}